// Round 1
// baseline (2126.407 us; speedup 1.0000x reference)
//
#include <hip/hip_runtime.h>

// MoE top-2, B=8 T=4096 D=512 H=1536 E=8.
// Strategy: fp64 gating + routed per-expert bf16 MFMA FFN (fused w1/w3/silu/w2),
// fp32 atomicAdd combine into out.

#define N_TOK 32768
#define DIM   512
#define HID   1536
#define NE    8

typedef __attribute__((ext_vector_type(8))) short  short8;
typedef __attribute__((ext_vector_type(4))) float  floatx4;

__device__ __forceinline__ unsigned short f2bf(float f) {
  unsigned int u = __float_as_uint(f);
  u += 0x7fffu + ((u >> 16) & 1u);   // round-to-nearest-even
  return (unsigned short)(u >> 16);
}

// ---------------- fp32 -> bf16 weight conversion ----------------
__global__ void __launch_bounds__(256) cvt_kernel(const float* __restrict__ src,
                                                  unsigned short* __restrict__ dst,
                                                  int n4) {
  int i = blockIdx.x * 256 + threadIdx.x;
  if (i >= n4) return;
  float4 v = ((const float4*)src)[i];
  unsigned int lo = (unsigned int)f2bf(v.x) | ((unsigned int)f2bf(v.y) << 16);
  unsigned int hi = (unsigned int)f2bf(v.z) | ((unsigned int)f2bf(v.w) << 16);
  uint2 o; o.x = lo; o.y = hi;
  ((uint2*)dst)[i] = o;
}

// ---------------- gating: logits (fp64 accum), top-2, softmax, route ----------------
__global__ void __launch_bounds__(256) gate_kernel(const float* __restrict__ x,
                                                   const float* __restrict__ gw,
                                                   int* __restrict__ tokl,
                                                   float* __restrict__ wgtl,
                                                   int* __restrict__ cnt) {
  int lane = threadIdx.x & 63;
  int wave = threadIdx.x >> 6;
  int t = blockIdx.x * 4 + wave;

  const float4* xp = (const float4*)(x + (size_t)t * DIM + lane * 8);
  float4 x0 = xp[0], x1 = xp[1];

  double p[NE];
#pragma unroll
  for (int e = 0; e < NE; ++e) {
    const float4* gp = (const float4*)(gw + e * DIM + lane * 8);
    float4 g0 = gp[0], g1 = gp[1];
    p[e] = (double)x0.x * g0.x + (double)x0.y * g0.y + (double)x0.z * g0.z + (double)x0.w * g0.w
         + (double)x1.x * g1.x + (double)x1.y * g1.y + (double)x1.z * g1.z + (double)x1.w * g1.w;
  }
#pragma unroll
  for (int m = 1; m < 64; m <<= 1) {
#pragma unroll
    for (int e = 0; e < NE; ++e) p[e] += __shfl_xor(p[e], m);
  }
  if (lane == 0) {
    double m1 = -1e300, m2 = -1e300; int i1 = 0, i2 = 0;
#pragma unroll
    for (int e = 0; e < NE; ++e) {
      double v = p[e];
      if (v > m1) { m2 = m1; i2 = i1; m1 = v; i1 = e; }
      else if (v > m2) { m2 = v; i2 = e; }
    }
    float e2 = __expf((float)(m2 - m1));
    float wa = 1.f / (1.f + e2);
    float wb = e2 * wa;
    int pos1 = atomicAdd(&cnt[i1], 1);
    tokl[i1 * N_TOK + pos1] = t;  wgtl[i1 * N_TOK + pos1] = wa;
    int pos2 = atomicAdd(&cnt[i2], 1);
    tokl[i2 * N_TOK + pos2] = t;  wgtl[i2 * N_TOK + pos2] = wb;
  }
}

// ---------------- fused FFN per (expert, 32-token tile) ----------------
#define MFMA(a, b, c) __builtin_amdgcn_mfma_f32_16x16x32_bf16(a, b, c, 0, 0, 0)

__global__ void __launch_bounds__(256) ffn_kernel(const float* __restrict__ x,
                                                  const unsigned short* __restrict__ w1b,
                                                  const unsigned short* __restrict__ w3b,
                                                  const unsigned short* __restrict__ w2b,
                                                  const int* __restrict__ tokl,
                                                  const float* __restrict__ wgtl,
                                                  const int* __restrict__ cnt,
                                                  float* __restrict__ out) {
  int e    = blockIdx.x & 7;     // expert = blockIdx%8 -> per-XCD L2 affinity
  int tile = blockIdx.x >> 3;
  int ne   = cnt[e];
  int m0   = tile * 32;
  if (m0 >= ne) return;

  __shared__ __align__(16) unsigned short Xt[32][520];  // +8 pad: b128 reads 2-way (free)
  __shared__ __align__(16) unsigned short Hc[32][72];   // stride 144B = 9*16, aligned
  __shared__ int   toks[32];
  __shared__ float wgts[32];

  int tid = threadIdx.x;
  if (tid < 32) {
    int idx = m0 + tid;
    if (idx < ne) { toks[tid] = tokl[e * N_TOK + idx]; wgts[tid] = wgtl[e * N_TOK + idx]; }
    else          { toks[tid] = tokl[e * N_TOK + m0];  wgts[tid] = 0.f; }
  }
  __syncthreads();

  // stage X tile (gather fp32 -> bf16 LDS)
  {
    int r  = tid >> 3;
    int c0 = (tid & 7) * 64;
    const float4* xr = (const float4*)(x + (size_t)toks[r] * DIM + c0);
#pragma unroll
    for (int j = 0; j < 16; ++j) {
      float4 v = xr[j];
      unsigned int lo = (unsigned int)f2bf(v.x) | ((unsigned int)f2bf(v.y) << 16);
      unsigned int hi = (unsigned int)f2bf(v.z) | ((unsigned int)f2bf(v.w) << 16);
      uint2 o; o.x = lo; o.y = hi;
      *(uint2*)&Xt[r][c0 + j * 4] = o;
    }
  }
  __syncthreads();

  int wave = tid >> 6, lane = tid & 63;
  int quad = lane >> 4, l16 = lane & 15;

  floatx4 zero4 = {0.f, 0.f, 0.f, 0.f};
  floatx4 accO[2][8];
#pragma unroll
  for (int m = 0; m < 2; ++m)
#pragma unroll
    for (int n = 0; n < 8; ++n) accO[m][n] = zero4;

  const unsigned short* w1base = w1b + ((size_t)(e * HID + wave * 16 + l16)) * DIM + quad * 8;
  const unsigned short* w3base = w3b + ((size_t)(e * HID + wave * 16 + l16)) * DIM + quad * 8;
  const unsigned short* w2base = w2b + ((size_t)(e * DIM + wave * 128 + l16)) * HID + quad * 8;

  for (int h0 = 0; h0 < HID; h0 += 64) {
    floatx4 a1[2], a3[2];
    a1[0] = zero4; a1[1] = zero4; a3[0] = zero4; a3[1] = zero4;

    const unsigned short* w1p = w1base + (size_t)h0 * DIM;
    const unsigned short* w3p = w3base + (size_t)h0 * DIM;
#pragma unroll
    for (int k0 = 0; k0 < DIM; k0 += 32) {
      short8 af0 = *(const short8*)&Xt[l16][k0 + quad * 8];
      short8 af1 = *(const short8*)&Xt[16 + l16][k0 + quad * 8];
      short8 b1  = *(const short8*)(w1p + k0);
      short8 b3  = *(const short8*)(w3p + k0);
      a1[0] = MFMA(af0, b1, a1[0]);
      a1[1] = MFMA(af1, b1, a1[1]);
      a3[0] = MFMA(af0, b3, a3[0]);
      a3[1] = MFMA(af1, b3, a3[1]);
    }
    // silu(u)*v -> Hc (bf16)
#pragma unroll
    for (int m = 0; m < 2; ++m)
#pragma unroll
      for (int r = 0; r < 4; ++r) {
        float u = a1[m][r], v = a3[m][r];
        float hv = (u / (1.f + __expf(-u))) * v;
        Hc[m * 16 + quad * 4 + r][wave * 16 + l16] = f2bf(hv);
      }
    __syncthreads();

    // out[32x512] += Hc[32x64] @ w2[:, h0:h0+64]^T
#pragma unroll
    for (int k2 = 0; k2 < 64; k2 += 32) {
      short8 ha0 = *(const short8*)&Hc[l16][k2 + quad * 8];
      short8 ha1 = *(const short8*)&Hc[16 + l16][k2 + quad * 8];
      const unsigned short* w2p = w2base + h0 + k2;
#pragma unroll
      for (int n = 0; n < 8; ++n) {
        short8 b2 = *(const short8*)(w2p + (size_t)n * 16 * HID);
        accO[0][n] = MFMA(ha0, b2, accO[0][n]);
        accO[1][n] = MFMA(ha1, b2, accO[1][n]);
      }
    }
    __syncthreads();
  }

  // weighted scatter-add into out
#pragma unroll
  for (int m = 0; m < 2; ++m)
#pragma unroll
    for (int n = 0; n < 8; ++n)
#pragma unroll
      for (int r = 0; r < 4; ++r) {
        int row = m * 16 + quad * 4 + r;
        int col = wave * 128 + n * 16 + l16;
        atomicAdd(&out[(size_t)toks[row] * DIM + col], wgts[row] * accO[m][n][r]);
      }
}

extern "C" void kernel_launch(void* const* d_in, const int* in_sizes, int n_in,
                              void* d_out, int out_size, void* d_ws, size_t ws_size,
                              hipStream_t stream) {
  const float* x  = (const float*)d_in[0];
  const float* gw = (const float*)d_in[1];
  const float* w1 = (const float*)d_in[2];
  const float* w3 = (const float*)d_in[3];
  const float* w2 = (const float*)d_in[4];
  float* out = (float*)d_out;

  const size_t NW = (size_t)NE * HID * DIM;  // 6291456 elements per weight tensor
  unsigned short* w1b = (unsigned short*)d_ws;
  unsigned short* w3b = w1b + NW;
  unsigned short* w2b = w3b + NW;
  int*   tokl = (int*)(w2b + NW);
  float* wgtl = (float*)(tokl + NE * N_TOK);
  int*   cnt  = (int*)(wgtl + NE * N_TOK);

  size_t needed = NW * 3 * 2 + (size_t)NE * N_TOK * 8 + 32;
  if (ws_size < needed) return;  // fail loudly (validation will catch)

  hipMemsetAsync(d_out, 0, (size_t)N_TOK * DIM * sizeof(float), stream);
  hipMemsetAsync(cnt, 0, NE * sizeof(int), stream);

  int n4 = (int)(NW / 4);
  int cvtBlocks = n4 / 256;  // 6144, exact
  cvt_kernel<<<cvtBlocks, 256, 0, stream>>>(w1, w1b, n4);
  cvt_kernel<<<cvtBlocks, 256, 0, stream>>>(w3, w3b, n4);
  cvt_kernel<<<cvtBlocks, 256, 0, stream>>>(w2, w2b, n4);

  gate_kernel<<<N_TOK / 4, 256, 0, stream>>>(x, gw, tokl, wgtl, cnt);

  // 1024 tile-slots per expert (worst case all tokens on one expert), expert = blockIdx%8
  ffn_kernel<<<8 * (N_TOK / 32), 256, 0, stream>>>(x, w1b, w3b, w2b, tokl, wgtl, cnt, out);
}

// Round 2
// 1881.218 us; speedup vs baseline: 1.1303x; 1.1303x over previous
//
#include <hip/hip_runtime.h>

// MoE top-2, B=8 T=4096 D=512 H=1536 E=8.
// R2: (a) contention-free 2-phase gating (R1 lost ~850us to 65536 serialized
// atomics on 8 counters); (b) FFN as two large tiled MFMA GEMMs (M=128) with
// H materialized in ws panels -> 4x less L2 weight traffic than M=32 fused.

#define N_TOK 32768
#define DIM   512
#define HID   1536
#define NE    8

typedef __attribute__((ext_vector_type(8))) short  short8;
typedef __attribute__((ext_vector_type(4))) float  floatx4;

#define MFMA(a, b, c) __builtin_amdgcn_mfma_f32_16x16x32_bf16(a, b, c, 0, 0, 0)

__device__ __forceinline__ unsigned short f2bf(float f) {
  unsigned int u = __float_as_uint(f);
  u += 0x7fffu + ((u >> 16) & 1u);   // round-to-nearest-even
  return (unsigned short)(u >> 16);
}
__device__ __forceinline__ unsigned pk2(float a, float b) {
  return (unsigned)f2bf(a) | ((unsigned)f2bf(b) << 16);
}

// ---------------- fp32 -> bf16 weight conversion ----------------
__global__ void __launch_bounds__(256) cvt_kernel(const float* __restrict__ src,
                                                  unsigned short* __restrict__ dst,
                                                  int n4) {
  int i = blockIdx.x * 256 + threadIdx.x;
  if (i >= n4) return;
  float4 v = ((const float4*)src)[i];
  uint2 o; o.x = pk2(v.x, v.y); o.y = pk2(v.z, v.w);
  ((uint2*)dst)[i] = o;
}

// ---------------- gate phase 1: logits (fp64), top-2, softmax ----------------
__global__ void __launch_bounds__(256) gate1_kernel(const float* __restrict__ x,
                                                    const float* __restrict__ gw,
                                                    unsigned* __restrict__ eidx,
                                                    float* __restrict__ wts) {
  int lane = threadIdx.x & 63;
  int wave = threadIdx.x >> 6;
  int t = blockIdx.x * 4 + wave;

  const float4* xp = (const float4*)(x + (size_t)t * DIM + lane * 8);
  float4 x0 = xp[0], x1 = xp[1];

  double p[NE];
#pragma unroll
  for (int e = 0; e < NE; ++e) {
    const float4* gp = (const float4*)(gw + e * DIM + lane * 8);
    float4 g0 = gp[0], g1 = gp[1];
    p[e] = (double)x0.x * g0.x + (double)x0.y * g0.y + (double)x0.z * g0.z + (double)x0.w * g0.w
         + (double)x1.x * g1.x + (double)x1.y * g1.y + (double)x1.z * g1.z + (double)x1.w * g1.w;
  }
#pragma unroll
  for (int m = 1; m < 64; m <<= 1) {
#pragma unroll
    for (int e = 0; e < NE; ++e) p[e] += __shfl_xor(p[e], m);
  }
  if (lane == 0) {
    double m1 = -1e300, m2 = -1e300; int i1 = 0, i2 = 0;
#pragma unroll
    for (int e = 0; e < NE; ++e) {
      double v = p[e];
      if (v > m1) { m2 = m1; i2 = i1; m1 = v; i1 = e; }
      else if (v > m2) { m2 = v; i2 = e; }
    }
    float e2 = __expf((float)(m2 - m1));
    float wa = 1.f / (1.f + e2);
    eidx[t] = (unsigned)i1 | ((unsigned)i2 << 8);
    wts[t]  = wa;
  }
}

// ---------------- gate phase 2: build per-expert lists (LDS hist + range reserve) ----
__global__ void __launch_bounds__(256) gate2_kernel(const unsigned* __restrict__ eidx,
                                                    const float* __restrict__ wts,
                                                    int* __restrict__ tokl,
                                                    float* __restrict__ wgtl,
                                                    int* __restrict__ cnt) {
  __shared__ unsigned hist[NE];
  __shared__ unsigned basep[NE];
  int tid = threadIdx.x;
  if (tid < NE) hist[tid] = 0;
  __syncthreads();
  int t0 = blockIdx.x * 1024;
  unsigned pk[4]; float wv[4];
#pragma unroll
  for (int i = 0; i < 4; ++i) {
    int t = t0 + tid + i * 256;
    pk[i] = eidx[t]; wv[i] = wts[t];
    atomicAdd(&hist[pk[i] & 0xff], 1u);
    atomicAdd(&hist[(pk[i] >> 8) & 0xff], 1u);
  }
  __syncthreads();
  if (tid < NE) {
    basep[tid] = (unsigned)atomicAdd(&cnt[tid], (int)hist[tid]);
    hist[tid] = 0;
  }
  __syncthreads();
#pragma unroll
  for (int i = 0; i < 4; ++i) {
    int t = t0 + tid + i * 256;
    int e1 = pk[i] & 0xff, e2 = (pk[i] >> 8) & 0xff;
    unsigned p1 = basep[e1] + atomicAdd(&hist[e1], 1u);
    tokl[e1 * N_TOK + p1] = t; wgtl[e1 * N_TOK + p1] = wv[i];
    unsigned p2 = basep[e2] + atomicAdd(&hist[e2], 1u);
    tokl[e2 * N_TOK + p2] = t; wgtl[e2 * N_TOK + p2] = 1.f - wv[i];
  }
}

// ---------------- GEMM1: Hs = silu(X w1^T) * (X w3^T), bf16 out -----------------
// block: 128 tokens x 64 h-cols, K=512 in BK=64 chunks. grid (mt-major, nt inner).
__global__ void __launch_bounds__(256) ffn1_kernel(const float* __restrict__ x,
                                                   const unsigned short* __restrict__ w1b,
                                                   const unsigned short* __restrict__ w3b,
                                                   const int* __restrict__ tokl,
                                                   const int* __restrict__ cnt,
                                                   unsigned short* __restrict__ Hs,
                                                   int h0base, int P, int NT) {
  int e  = blockIdx.x & 7;
  int t  = blockIdx.x >> 3;
  int nt = t % NT;
  int mt = t / NT;
  int ne = cnt[e];
  int m0 = mt * 128;
  if (m0 >= ne) return;
  int offs = 0;
#pragma unroll
  for (int i = 0; i < NE; ++i) offs += (i < e) ? cnt[i] : 0;

  __shared__ __align__(16) unsigned short Xa[128][72];  // stride 144B = 9*16B: conflict-free
  __shared__ int toks[128];

  int tid = threadIdx.x;
  if (tid < 128) {
    int r = m0 + tid;
    toks[tid] = tokl[e * N_TOK + (r < ne ? r : 0)];
  }
  __syncthreads();

  int wave = tid >> 6, lane = tid & 63, quad = lane >> 4, l16 = lane & 15;
  int n0 = nt * 64;  // panel-local h col base

  floatx4 z = {0.f, 0.f, 0.f, 0.f};
  floatx4 u[2][4], v[2][4];
#pragma unroll
  for (int m = 0; m < 2; ++m)
#pragma unroll
    for (int n = 0; n < 4; ++n) { u[m][n] = z; v[m][n] = z; }

  const unsigned short* w1p = w1b + ((size_t)e * HID + h0base + n0 + l16) * DIM + quad * 8;
  const unsigned short* w3p = w3b + ((size_t)e * HID + h0base + n0 + l16) * DIM + quad * 8;

  int srow = tid >> 1, shalf = tid & 1;
  const float* xsrc = x + (size_t)toks[srow] * DIM + shalf * 32;
  unsigned short* sdst = &Xa[srow][shalf * 32];

  for (int k0 = 0; k0 < DIM; k0 += 64) {
    // stage 128x64 fp32 -> bf16 LDS (2 threads/row, 32 floats each)
    float4 f[8];
#pragma unroll
    for (int j = 0; j < 8; ++j) f[j] = ((const float4*)(xsrc + k0))[j];
#pragma unroll
    for (int j = 0; j < 4; ++j) {
      uint4 o;
      o.x = pk2(f[2*j].x,   f[2*j].y);
      o.y = pk2(f[2*j].z,   f[2*j].w);
      o.z = pk2(f[2*j+1].x, f[2*j+1].y);
      o.w = pk2(f[2*j+1].z, f[2*j+1].w);
      *(uint4*)(sdst + j * 8) = o;
    }
    __syncthreads();
#pragma unroll
    for (int kk = 0; kk < 2; ++kk) {
      int kc = k0 + kk * 32;
      short8 a0 = *(const short8*)&Xa[wave * 32 + l16][kk * 32 + quad * 8];
      short8 a1 = *(const short8*)&Xa[wave * 32 + 16 + l16][kk * 32 + quad * 8];
#pragma unroll
      for (int n = 0; n < 4; ++n) {
        short8 b1 = *(const short8*)(w1p + (size_t)n * 16 * DIM + kc);
        short8 b3 = *(const short8*)(w3p + (size_t)n * 16 * DIM + kc);
        u[0][n] = MFMA(a0, b1, u[0][n]);
        u[1][n] = MFMA(a1, b1, u[1][n]);
        v[0][n] = MFMA(a0, b3, v[0][n]);
        v[1][n] = MFMA(a1, b3, v[1][n]);
      }
    }
    __syncthreads();
  }

  // silu(u)*v -> LDS (reuse Xa) -> coalesced bf16 store to Hs
#pragma unroll
  for (int m = 0; m < 2; ++m)
#pragma unroll
    for (int n = 0; n < 4; ++n)
#pragma unroll
      for (int r = 0; r < 4; ++r) {
        float uu = u[m][n][r], vv = v[m][n][r];
        float hv = (uu / (1.f + __expf(-uu))) * vv;
        Xa[wave * 32 + m * 16 + quad * 4 + r][n * 16 + l16] = f2bf(hv);
      }
  __syncthreads();
  {
    int row = tid >> 1;
    if (m0 + row < ne) {
      unsigned short* dst = Hs + (size_t)(offs + m0 + row) * P + n0 + shalf * 32;
      const unsigned short* srcl = &Xa[row][shalf * 32];
#pragma unroll
      for (int j = 0; j < 4; ++j)
        *(uint4*)(dst + j * 8) = *(const uint4*)(srcl + j * 8);
    }
  }
}

// ---------------- GEMM2: out += combine * (Hs @ w2^T) ----------------
// block: 128 tokens x 64 d-cols, K=P in BK=64 chunks.
__global__ void __launch_bounds__(256) ffn2_kernel(const unsigned short* __restrict__ Hs,
                                                   const unsigned short* __restrict__ w2b,
                                                   const int* __restrict__ tokl,
                                                   const float* __restrict__ wgtl,
                                                   const int* __restrict__ cnt,
                                                   float* __restrict__ out,
                                                   int h0base, int P) {
  int e  = blockIdx.x & 7;
  int t  = blockIdx.x >> 3;
  int nt = t & 7;       // 8 d-tiles of 64
  int mt = t >> 3;
  int ne = cnt[e];
  int m0 = mt * 128;
  if (m0 >= ne) return;
  int offs = 0;
#pragma unroll
  for (int i = 0; i < NE; ++i) offs += (i < e) ? cnt[i] : 0;

  __shared__ __align__(16) unsigned short Ha[128][72];
  __shared__ int   toks[128];
  __shared__ float wg[128];

  int tid = threadIdx.x;
  if (tid < 128) {
    int r = m0 + tid; bool ok = r < ne;
    toks[tid] = tokl[e * N_TOK + (ok ? r : 0)];
    wg[tid]   = ok ? wgtl[e * N_TOK + r] : 0.f;
  }
  __syncthreads();

  int wave = tid >> 6, lane = tid & 63, quad = lane >> 4, l16 = lane & 15;
  int n0 = nt * 64;

  floatx4 z = {0.f, 0.f, 0.f, 0.f};
  floatx4 o[2][4];
#pragma unroll
  for (int m = 0; m < 2; ++m)
#pragma unroll
    for (int n = 0; n < 4; ++n) o[m][n] = z;

  const unsigned short* w2p = w2b + ((size_t)e * DIM + n0 + l16) * HID + h0base + quad * 8;

  int srow = tid >> 1, shalf = tid & 1;
  const unsigned short* hsrc = Hs + (size_t)(offs + m0 + srow) * P + shalf * 32;
  unsigned short* sdst = &Ha[srow][shalf * 32];

  for (int k0 = 0; k0 < P; k0 += 64) {
#pragma unroll
    for (int j = 0; j < 4; ++j)
      *(uint4*)(sdst + j * 8) = *(const uint4*)(hsrc + k0 + j * 8);
    __syncthreads();
#pragma unroll
    for (int kk = 0; kk < 2; ++kk) {
      short8 a0 = *(const short8*)&Ha[wave * 32 + l16][kk * 32 + quad * 8];
      short8 a1 = *(const short8*)&Ha[wave * 32 + 16 + l16][kk * 32 + quad * 8];
#pragma unroll
      for (int n = 0; n < 4; ++n) {
        short8 b = *(const short8*)(w2p + (size_t)n * 16 * HID + k0 + kk * 32);
        o[0][n] = MFMA(a0, b, o[0][n]);
        o[1][n] = MFMA(a1, b, o[1][n]);
      }
    }
    __syncthreads();
  }

#pragma unroll
  for (int m = 0; m < 2; ++m)
#pragma unroll
    for (int n = 0; n < 4; ++n)
#pragma unroll
      for (int r = 0; r < 4; ++r) {
        int row = wave * 32 + m * 16 + quad * 4 + r;
        if (m0 + row < ne)
          atomicAdd(&out[(size_t)toks[row] * DIM + n0 + n * 16 + l16],
                    wg[row] * o[m][n][r]);
      }
}

extern "C" void kernel_launch(void* const* d_in, const int* in_sizes, int n_in,
                              void* d_out, int out_size, void* d_ws, size_t ws_size,
                              hipStream_t stream) {
  const float* x  = (const float*)d_in[0];
  const float* gw = (const float*)d_in[1];
  const float* w1 = (const float*)d_in[2];
  const float* w3 = (const float*)d_in[3];
  const float* w2 = (const float*)d_in[4];
  float* out = (float*)d_out;

  const size_t NW = (size_t)NE * HID * DIM;  // 6,291,456
  char* p = (char*)d_ws;
  unsigned short* w1b = (unsigned short*)p;  p += NW * 2;
  unsigned short* w3b = (unsigned short*)p;  p += NW * 2;
  unsigned short* w2b = (unsigned short*)p;  p += NW * 2;
  int*      tokl = (int*)p;       p += (size_t)NE * N_TOK * 4;
  float*    wgtl = (float*)p;     p += (size_t)NE * N_TOK * 4;
  unsigned* eidx = (unsigned*)p;  p += (size_t)N_TOK * 4;
  float*    wts  = (float*)p;     p += (size_t)N_TOK * 4;
  int*      cnt  = (int*)p;       p += 256;
  unsigned short* Hs = (unsigned short*)p;
  size_t fixed = (size_t)(p - (char*)d_ws);
  if (ws_size < fixed) return;
  size_t avail = ws_size - fixed;

  // panel width: largest divisor of 1536 whose Hs fits
  const int cands[5] = {1536, 768, 512, 384, 256};
  int P = 0;
  for (int i = 0; i < 5; ++i)
    if ((size_t)(65536 + 128) * cands[i] * 2 <= avail) { P = cands[i]; break; }
  if (!P) return;

  hipMemsetAsync(d_out, 0, (size_t)N_TOK * DIM * sizeof(float), stream);
  hipMemsetAsync(cnt, 0, NE * sizeof(int), stream);

  int n4 = (int)(NW / 4);
  cvt_kernel<<<n4 / 256, 256, 0, stream>>>(w1, w1b, n4);
  cvt_kernel<<<n4 / 256, 256, 0, stream>>>(w3, w3b, n4);
  cvt_kernel<<<n4 / 256, 256, 0, stream>>>(w2, w2b, n4);

  gate1_kernel<<<N_TOK / 4, 256, 0, stream>>>(x, gw, eidx, wts);
  gate2_kernel<<<N_TOK / 1024, 256, 0, stream>>>(eidx, wts, tokl, wgtl, cnt);

  for (int h0 = 0; h0 < HID; h0 += P) {
    int NT = P / 64;
    ffn1_kernel<<<8 * 256 * NT, 256, 0, stream>>>(x, w1b, w3b, tokl, cnt, Hs, h0, P, NT);
    ffn2_kernel<<<8 * 256 * 8, 256, 0, stream>>>(Hs, w2b, tokl, wgtl, cnt, out, h0, P);
  }
}

// Round 4
// 885.215 us; speedup vs baseline: 2.4021x; 2.1252x over previous
//
#include <hip/hip_runtime.h>

// MoE top-2, B=8 T=4096 D=512 H=1536 E=8.
// R4 = R3 with ffn2 epilogue column fix (wn*64, was wn*0).
// m97-style GEMMs: global_load_lds(16B) staging for A and B with XOR-swizzled
// LDS chunks, 128x128 tiles, BK=64. x converted to bf16 once (in gate1).
// ffn1 computes U|V in one block (N=128 = 64 w1-rows | 64 w3-rows), silu-combines
// via LDS exchange, folds gate weight into Hs. ffn2 = plain GEMM + atomicAdd.

#define N_TOK 32768
#define DIM   512
#define HID   1536
#define NE    8
#define MTS   256   // max 128-row tiles per expert (worst case ne=32768)

typedef __attribute__((ext_vector_type(8))) short  short8;
typedef __attribute__((ext_vector_type(4))) float  floatx4;

#define MFMA(a,b,c) __builtin_amdgcn_mfma_f32_16x16x32_bf16(a,b,c,0,0,0)

__device__ __forceinline__ unsigned short f2bf(float f) {
  unsigned int u = __float_as_uint(f);
  u += 0x7fffu + ((u >> 16) & 1u);
  return (unsigned short)(u >> 16);
}
__device__ __forceinline__ unsigned pk2(float a, float b) {
  return (unsigned)f2bf(a) | ((unsigned)f2bf(b) << 16);
}
__device__ __forceinline__ float bf2f(unsigned short b) {
  return __uint_as_float(((unsigned)b) << 16);
}
// async global->LDS, 16B per lane; dst = wave-uniform base + lane*16
__device__ __forceinline__ void gl_lds16(const unsigned short* g, unsigned short* l) {
  __builtin_amdgcn_global_load_lds(
      (const __attribute__((address_space(1))) unsigned int*)g,
      (__attribute__((address_space(3))) unsigned int*)l, 16, 0, 0);
}

// ---------------- fp32 -> bf16 weight conversion ----------------
__global__ void __launch_bounds__(256) cvt_kernel(const float* __restrict__ src,
                                                  unsigned short* __restrict__ dst,
                                                  int n4) {
  int i = blockIdx.x * 256 + threadIdx.x;
  if (i >= n4) return;
  float4 v = ((const float4*)src)[i];
  uint2 o; o.x = pk2(v.x, v.y); o.y = pk2(v.z, v.w);
  ((uint2*)dst)[i] = o;
}

// ------------- gate phase 1: logits (fp64), top-2, softmax; also x->bf16 -------------
__global__ void __launch_bounds__(256) gate1_kernel(const float* __restrict__ x,
                                                    const float* __restrict__ gw,
                                                    unsigned short* __restrict__ xb,
                                                    unsigned* __restrict__ eidx,
                                                    float* __restrict__ wts) {
  int lane = threadIdx.x & 63;
  int wave = threadIdx.x >> 6;
  int t = blockIdx.x * 4 + wave;

  const float4* xp = (const float4*)(x + (size_t)t * DIM + lane * 8);
  float4 x0 = xp[0], x1 = xp[1];

  uint4 o; o.x = pk2(x0.x, x0.y); o.y = pk2(x0.z, x0.w);
  o.z = pk2(x1.x, x1.y); o.w = pk2(x1.z, x1.w);
  *(uint4*)(xb + (size_t)t * DIM + lane * 8) = o;

  double p[NE];
#pragma unroll
  for (int e = 0; e < NE; ++e) {
    const float4* gp = (const float4*)(gw + e * DIM + lane * 8);
    float4 g0 = gp[0], g1 = gp[1];
    p[e] = (double)x0.x * g0.x + (double)x0.y * g0.y + (double)x0.z * g0.z + (double)x0.w * g0.w
         + (double)x1.x * g1.x + (double)x1.y * g1.y + (double)x1.z * g1.z + (double)x1.w * g1.w;
  }
#pragma unroll
  for (int m = 1; m < 64; m <<= 1) {
#pragma unroll
    for (int e = 0; e < NE; ++e) p[e] += __shfl_xor(p[e], m);
  }
  if (lane == 0) {
    double m1 = -1e300, m2 = -1e300; int i1 = 0, i2 = 0;
#pragma unroll
    for (int e = 0; e < NE; ++e) {
      double v = p[e];
      if (v > m1) { m2 = m1; i2 = i1; m1 = v; i1 = e; }
      else if (v > m2) { m2 = v; i2 = e; }
    }
    float e2 = __expf((float)(m2 - m1));
    float wa = 1.f / (1.f + e2);
    eidx[t] = (unsigned)i1 | ((unsigned)i2 << 8);
    wts[t]  = wa;
  }
}

// ---------------- gate phase 2: per-expert lists (LDS hist + range reserve) ----------
__global__ void __launch_bounds__(256) gate2_kernel(const unsigned* __restrict__ eidx,
                                                    const float* __restrict__ wts,
                                                    int* __restrict__ tokl,
                                                    float* __restrict__ wgtl,
                                                    int* __restrict__ cnt) {
  __shared__ unsigned hist[NE];
  __shared__ unsigned basep[NE];
  int tid = threadIdx.x;
  if (tid < NE) hist[tid] = 0;
  __syncthreads();
  int t0 = blockIdx.x * 1024;
  unsigned pk[4]; float wv[4];
#pragma unroll
  for (int i = 0; i < 4; ++i) {
    int t = t0 + tid + i * 256;
    pk[i] = eidx[t]; wv[i] = wts[t];
    atomicAdd(&hist[pk[i] & 0xff], 1u);
    atomicAdd(&hist[(pk[i] >> 8) & 0xff], 1u);
  }
  __syncthreads();
  if (tid < NE) {
    basep[tid] = (unsigned)atomicAdd(&cnt[tid], (int)hist[tid]);
    hist[tid] = 0;
  }
  __syncthreads();
#pragma unroll
  for (int i = 0; i < 4; ++i) {
    int t = t0 + tid + i * 256;
    int e1 = pk[i] & 0xff, e2 = (pk[i] >> 8) & 0xff;
    unsigned p1 = basep[e1] + atomicAdd(&hist[e1], 1u);
    tokl[e1 * N_TOK + p1] = t; wgtl[e1 * N_TOK + p1] = wv[i];
    unsigned p2 = basep[e2] + atomicAdd(&hist[e2], 1u);
    tokl[e2 * N_TOK + p2] = t; wgtl[e2 * N_TOK + p2] = 1.f - wv[i];
  }
}

// ---------------- GEMM1: Hs = wgt * silu(X w1^T) * (X w3^T), bf16 ----------------
// tile: M=128 tokens x 64 h-cols (B rows: 64 w1 | 64 w3), BK=64.
__global__ void __launch_bounds__(256) ffn1_kernel(
    const unsigned short* __restrict__ xb,
    const unsigned short* __restrict__ w1b,
    const unsigned short* __restrict__ w3b,
    const int* __restrict__ tokl, const float* __restrict__ wgtl,
    const int* __restrict__ cnt,
    unsigned short* __restrict__ Hs,
    int h0base, int P, int NT) {
  int e  = blockIdx.x & 7;
  int t  = blockIdx.x >> 3;
  int nt = t % NT, mt = t / NT;
  int ne = cnt[e];
  int m0 = mt * 128;
  if (m0 >= ne) return;
  int offs = 0;
#pragma unroll
  for (int i = 0; i < NE; ++i) offs += (i < e) ? cnt[i] : 0;

  __shared__ __align__(16) unsigned short As[128 * 64];   // swizzled chunks
  __shared__ __align__(16) unsigned short Bs[128 * 64];
  __shared__ float wgs[128];

  int tid = threadIdx.x, w = tid >> 6, lane = tid & 63;
  int quad = lane >> 4, l16 = lane & 15;
  int wm = w >> 1, wn = w & 1;

  if (tid < 128) {
    int r = m0 + tid;
    wgs[tid] = (r < ne) ? wgtl[e * N_TOK + r] : 0.f;
  }

  int rl = lane >> 3, cs = lane & 7, cc = cs ^ rl;   // source chunk col (XOR swizzle)
  const unsigned short* pa[4];
  const unsigned short* pb[4];
  int hbase = h0base + nt * 64;
  const unsigned short* wsrc = (w < 2) ? w1b : w3b;
#pragma unroll
  for (int i = 0; i < 4; ++i) {
    int r = m0 + 32 * w + 8 * i + rl;
    int tok = tokl[e * N_TOK + (r < ne ? r : m0)];
    pa[i] = xb + (size_t)tok * DIM + cc * 8;
    int rb = (32 * w + 8 * i + rl) & 63;
    pb[i] = wsrc + ((size_t)e * HID + hbase + rb) * DIM + cc * 8;
  }

  floatx4 acc[4][4];
#pragma unroll
  for (int i = 0; i < 4; ++i)
#pragma unroll
    for (int j = 0; j < 4; ++j) acc[i][j] = (floatx4){0.f, 0.f, 0.f, 0.f};

  for (int k0 = 0; k0 < DIM; k0 += 64) {
#pragma unroll
    for (int i = 0; i < 4; ++i) {
      gl_lds16(pa[i], &As[(32 * w + 8 * i) * 64]);
      gl_lds16(pb[i], &Bs[(32 * w + 8 * i) * 64]);
      pa[i] += 64; pb[i] += 64;
    }
    __syncthreads();
#pragma unroll
    for (int kk = 0; kk < 2; ++kk) {
      short8 a[4], b[4];
#pragma unroll
      for (int i = 0; i < 4; ++i) {
        int ra = wm * 64 + i * 16 + l16;
        a[i] = *(const short8*)&As[ra * 64 + (((4 * kk + quad) ^ (ra & 7)) * 8)];
        int rb = wn * 64 + i * 16 + l16;
        b[i] = *(const short8*)&Bs[rb * 64 + (((4 * kk + quad) ^ (rb & 7)) * 8)];
      }
#pragma unroll
      for (int i = 0; i < 4; ++i)
#pragma unroll
        for (int j = 0; j < 4; ++j)
          acc[i][j] = MFMA(a[i], b[j], acc[i][j]);
    }
    __syncthreads();
  }

  // ---- epilogue: V (wn==1) -> LDS, U waves combine, store Hs ----
  unsigned short* Vb = Bs;   // 128 x 64, plain layout
  if (wn == 1) {
#pragma unroll
    for (int i = 0; i < 4; ++i)
#pragma unroll
      for (int j = 0; j < 4; ++j)
#pragma unroll
        for (int r = 0; r < 4; ++r) {
          int row = wm * 64 + i * 16 + quad * 4 + r;
          Vb[row * 64 + j * 16 + l16] = f2bf(acc[i][j][r]);
        }
  }
  __syncthreads();
  unsigned short* Hb = As;   // 128 x 64, plain layout
  if (wn == 0) {
#pragma unroll
    for (int i = 0; i < 4; ++i)
#pragma unroll
      for (int j = 0; j < 4; ++j)
#pragma unroll
        for (int r = 0; r < 4; ++r) {
          int row = wm * 64 + i * 16 + quad * 4 + r;
          int col = j * 16 + l16;
          float u = acc[i][j][r];
          float v = bf2f(Vb[row * 64 + col]);
          float h = (u / (1.f + __expf(-u))) * v * wgs[row];
          Hb[row * 64 + col] = f2bf(h);
        }
  }
  __syncthreads();
  {
    int row = tid >> 1, half = tid & 1;
    if (m0 + row < ne) {
      const unsigned short* s = &Hb[row * 64 + half * 32];
      unsigned short* d = Hs + (size_t)(offs + m0 + row) * P + nt * 64 + half * 32;
#pragma unroll
      for (int j = 0; j < 4; ++j) *(uint4*)(d + j * 8) = *(const uint4*)(s + j * 8);
    }
  }
}

// ---------------- GEMM2: out += Hs @ w2^T (weight already folded) ----------------
// tile: M=128 tokens x N=128 d-cols, BK=64, K=P.
__global__ void __launch_bounds__(256) ffn2_kernel(
    const unsigned short* __restrict__ Hs,
    const unsigned short* __restrict__ w2b,
    const int* __restrict__ tokl, const int* __restrict__ cnt,
    float* __restrict__ out, int h0base, int P) {
  int e  = blockIdx.x & 7;
  int t  = blockIdx.x >> 3;
  int nt = t & 3, mt = t >> 2;
  int ne = cnt[e];
  int m0 = mt * 128;
  if (m0 >= ne) return;
  int offs = 0;
#pragma unroll
  for (int i = 0; i < NE; ++i) offs += (i < e) ? cnt[i] : 0;

  __shared__ __align__(16) unsigned short As[128 * 64];
  __shared__ __align__(16) unsigned short Bs[128 * 64];
  __shared__ int toks[128];

  int tid = threadIdx.x, w = tid >> 6, lane = tid & 63;
  int quad = lane >> 4, l16 = lane & 15;
  int wm = w >> 1, wn = w & 1;
  if (tid < 128) { int r = m0 + tid; toks[tid] = tokl[e * N_TOK + (r < ne ? r : m0)]; }

  int rl = lane >> 3, cs = lane & 7, cc = cs ^ rl;
  int dbase = nt * 128;
  const unsigned short* pa[4];
  const unsigned short* pb[4];
#pragma unroll
  for (int i = 0; i < 4; ++i) {
    int r = m0 + 32 * w + 8 * i + rl;             // may run past ne into pad rows (masked later)
    pa[i] = Hs + (size_t)(offs + r) * P + cc * 8;
    int rb = 32 * w + 8 * i + rl;
    pb[i] = w2b + ((size_t)e * DIM + dbase + rb) * HID + h0base + cc * 8;
  }

  floatx4 acc[4][4];
#pragma unroll
  for (int i = 0; i < 4; ++i)
#pragma unroll
    for (int j = 0; j < 4; ++j) acc[i][j] = (floatx4){0.f, 0.f, 0.f, 0.f};

  for (int k0 = 0; k0 < P; k0 += 64) {
#pragma unroll
    for (int i = 0; i < 4; ++i) {
      gl_lds16(pa[i], &As[(32 * w + 8 * i) * 64]);
      gl_lds16(pb[i], &Bs[(32 * w + 8 * i) * 64]);
      pa[i] += 64; pb[i] += 64;
    }
    __syncthreads();
#pragma unroll
    for (int kk = 0; kk < 2; ++kk) {
      short8 a[4], b[4];
#pragma unroll
      for (int i = 0; i < 4; ++i) {
        int ra = wm * 64 + i * 16 + l16;
        a[i] = *(const short8*)&As[ra * 64 + (((4 * kk + quad) ^ (ra & 7)) * 8)];
        int rb = wn * 64 + i * 16 + l16;
        b[i] = *(const short8*)&Bs[rb * 64 + (((4 * kk + quad) ^ (rb & 7)) * 8)];
      }
#pragma unroll
      for (int i = 0; i < 4; ++i)
#pragma unroll
        for (int j = 0; j < 4; ++j)
          acc[i][j] = MFMA(a[i], b[j], acc[i][j]);
    }
    __syncthreads();
  }

#pragma unroll
  for (int i = 0; i < 4; ++i)
#pragma unroll
    for (int j = 0; j < 4; ++j)
#pragma unroll
      for (int r = 0; r < 4; ++r) {
        int row = wm * 64 + i * 16 + quad * 4 + r;
        if (m0 + row < ne)
          atomicAdd(&out[(size_t)toks[row] * DIM + dbase + wn * 64 + j * 16 + l16],
                    acc[i][j][r]);
      }
}

extern "C" void kernel_launch(void* const* d_in, const int* in_sizes, int n_in,
                              void* d_out, int out_size, void* d_ws, size_t ws_size,
                              hipStream_t stream) {
  const float* x  = (const float*)d_in[0];
  const float* gw = (const float*)d_in[1];
  const float* w1 = (const float*)d_in[2];
  const float* w3 = (const float*)d_in[3];
  const float* w2 = (const float*)d_in[4];
  float* out = (float*)d_out;

  const size_t NW = (size_t)NE * HID * DIM;
  char* p = (char*)d_ws;
  unsigned short* w1b = (unsigned short*)p;  p += NW * 2;
  unsigned short* w3b = (unsigned short*)p;  p += NW * 2;
  unsigned short* w2b = (unsigned short*)p;  p += NW * 2;
  unsigned short* xb  = (unsigned short*)p;  p += (size_t)N_TOK * DIM * 2;
  int*      tokl = (int*)p;       p += (size_t)NE * N_TOK * 4;
  float*    wgtl = (float*)p;     p += (size_t)NE * N_TOK * 4;
  unsigned* eidx = (unsigned*)p;  p += (size_t)N_TOK * 4;
  float*    wts  = (float*)p;     p += (size_t)N_TOK * 4;
  int*      cnt  = (int*)p;       p += 256;
  unsigned short* Hs = (unsigned short*)p;
  size_t fixed = (size_t)(p - (char*)d_ws);
  if (ws_size < fixed) return;
  size_t avail = ws_size - fixed;

  const int cands[5] = {1536, 768, 512, 384, 256};
  int P = 0;
  for (int i = 0; i < 5; ++i)
    if ((size_t)(2 * N_TOK + 128) * cands[i] * 2 <= avail) { P = cands[i]; break; }
  if (!P) return;

  hipMemsetAsync(d_out, 0, (size_t)N_TOK * DIM * sizeof(float), stream);
  hipMemsetAsync(cnt, 0, NE * sizeof(int), stream);

  int n4 = (int)(NW / 4);
  cvt_kernel<<<n4 / 256, 256, 0, stream>>>(w1, w1b, n4);
  cvt_kernel<<<n4 / 256, 256, 0, stream>>>(w3, w3b, n4);
  cvt_kernel<<<n4 / 256, 256, 0, stream>>>(w2, w2b, n4);

  gate1_kernel<<<N_TOK / 4, 256, 0, stream>>>(x, gw, xb, eidx, wts);
  gate2_kernel<<<N_TOK / 1024, 256, 0, stream>>>(eidx, wts, tokl, wgtl, cnt);

  for (int h0 = 0; h0 < HID; h0 += P) {
    int NT = P / 64;
    ffn1_kernel<<<8 * MTS * NT, 256, 0, stream>>>(xb, w1b, w3b, tokl, wgtl, cnt, Hs, h0, P, NT);
    ffn2_kernel<<<8 * MTS * 4, 256, 0, stream>>>(Hs, w2b, tokl, cnt, out, h0, P);
  }
}

// Round 5
// 694.086 us; speedup vs baseline: 3.0636x; 1.2754x over previous
//
#include <hip/hip_runtime.h>

// MoE top-2, B=8 T=4096 D=512 H=1536 E=8.
// R5: occupancy push. R4 ran at 2 blocks/CU (112 VGPR + 64 AGPR unified ~ 176).
// __launch_bounds__(256,4) caps regs at 128 -> 4 blocks/CU. ffn1 restructured:
// B-tile = [w1_64 | w3_64] over same h-cols, waves hold matching u,v accs ->
// in-register silu, no LDS exchange (3 barriers -> 1). B staging via one base
// pointer + const strides (regs); A keeps 4 gathered pointers.

#define N_TOK 32768
#define DIM   512
#define HID   1536
#define NE    8
#define MTS   256   // max 128-row tiles per expert (worst case ne=32768)

typedef __attribute__((ext_vector_type(8))) short  short8;
typedef __attribute__((ext_vector_type(4))) float  floatx4;

#define MFMA(a,b,c) __builtin_amdgcn_mfma_f32_16x16x32_bf16(a,b,c,0,0,0)

__device__ __forceinline__ unsigned short f2bf(float f) {
  unsigned int u = __float_as_uint(f);
  u += 0x7fffu + ((u >> 16) & 1u);
  return (unsigned short)(u >> 16);
}
__device__ __forceinline__ unsigned pk2(float a, float b) {
  return (unsigned)f2bf(a) | ((unsigned)f2bf(b) << 16);
}
// async global->LDS, 16B per lane; dst = wave-uniform base + lane*16
__device__ __forceinline__ void gl_lds16(const unsigned short* g, unsigned short* l) {
  __builtin_amdgcn_global_load_lds(
      (const __attribute__((address_space(1))) unsigned int*)g,
      (__attribute__((address_space(3))) unsigned int*)l, 16, 0, 0);
}

// ---------------- fp32 -> bf16 weight conversion ----------------
__global__ void __launch_bounds__(256) cvt_kernel(const float* __restrict__ src,
                                                  unsigned short* __restrict__ dst,
                                                  int n4) {
  int i = blockIdx.x * 256 + threadIdx.x;
  if (i >= n4) return;
  float4 v = ((const float4*)src)[i];
  uint2 o; o.x = pk2(v.x, v.y); o.y = pk2(v.z, v.w);
  ((uint2*)dst)[i] = o;
}

// ------------- gate phase 1: logits (fp64), top-2, softmax; also x->bf16 -------------
__global__ void __launch_bounds__(256) gate1_kernel(const float* __restrict__ x,
                                                    const float* __restrict__ gw,
                                                    unsigned short* __restrict__ xb,
                                                    unsigned* __restrict__ eidx,
                                                    float* __restrict__ wts) {
  int lane = threadIdx.x & 63;
  int wave = threadIdx.x >> 6;
  int t = blockIdx.x * 4 + wave;

  const float4* xp = (const float4*)(x + (size_t)t * DIM + lane * 8);
  float4 x0 = xp[0], x1 = xp[1];

  uint4 o; o.x = pk2(x0.x, x0.y); o.y = pk2(x0.z, x0.w);
  o.z = pk2(x1.x, x1.y); o.w = pk2(x1.z, x1.w);
  *(uint4*)(xb + (size_t)t * DIM + lane * 8) = o;

  double p[NE];
#pragma unroll
  for (int e = 0; e < NE; ++e) {
    const float4* gp = (const float4*)(gw + e * DIM + lane * 8);
    float4 g0 = gp[0], g1 = gp[1];
    p[e] = (double)x0.x * g0.x + (double)x0.y * g0.y + (double)x0.z * g0.z + (double)x0.w * g0.w
         + (double)x1.x * g1.x + (double)x1.y * g1.y + (double)x1.z * g1.z + (double)x1.w * g1.w;
  }
#pragma unroll
  for (int m = 1; m < 64; m <<= 1) {
#pragma unroll
    for (int e = 0; e < NE; ++e) p[e] += __shfl_xor(p[e], m);
  }
  if (lane == 0) {
    double m1 = -1e300, m2 = -1e300; int i1 = 0, i2 = 0;
#pragma unroll
    for (int e = 0; e < NE; ++e) {
      double v = p[e];
      if (v > m1) { m2 = m1; i2 = i1; m1 = v; i1 = e; }
      else if (v > m2) { m2 = v; i2 = e; }
    }
    float e2 = __expf((float)(m2 - m1));
    float wa = 1.f / (1.f + e2);
    eidx[t] = (unsigned)i1 | ((unsigned)i2 << 8);
    wts[t]  = wa;
  }
}

// ---------------- gate phase 2: per-expert lists (LDS hist + range reserve) ----------
__global__ void __launch_bounds__(256) gate2_kernel(const unsigned* __restrict__ eidx,
                                                    const float* __restrict__ wts,
                                                    int* __restrict__ tokl,
                                                    float* __restrict__ wgtl,
                                                    int* __restrict__ cnt) {
  __shared__ unsigned hist[NE];
  __shared__ unsigned basep[NE];
  int tid = threadIdx.x;
  if (tid < NE) hist[tid] = 0;
  __syncthreads();
  int t0 = blockIdx.x * 1024;
  unsigned pk[4]; float wv[4];
#pragma unroll
  for (int i = 0; i < 4; ++i) {
    int t = t0 + tid + i * 256;
    pk[i] = eidx[t]; wv[i] = wts[t];
    atomicAdd(&hist[pk[i] & 0xff], 1u);
    atomicAdd(&hist[(pk[i] >> 8) & 0xff], 1u);
  }
  __syncthreads();
  if (tid < NE) {
    basep[tid] = (unsigned)atomicAdd(&cnt[tid], (int)hist[tid]);
    hist[tid] = 0;
  }
  __syncthreads();
#pragma unroll
  for (int i = 0; i < 4; ++i) {
    int t = t0 + tid + i * 256;
    int e1 = pk[i] & 0xff, e2 = (pk[i] >> 8) & 0xff;
    unsigned p1 = basep[e1] + atomicAdd(&hist[e1], 1u);
    tokl[e1 * N_TOK + p1] = t; wgtl[e1 * N_TOK + p1] = wv[i];
    unsigned p2 = basep[e2] + atomicAdd(&hist[e2], 1u);
    tokl[e2 * N_TOK + p2] = t; wgtl[e2 * N_TOK + p2] = 1.f - wv[i];
  }
}

// ---------------- GEMM1: Hs = wgt * silu(X w1^T) * (X w3^T), bf16 ----------------
// tile: 128 tokens x 64 h-cols. Bs = [w1 rows 0..63 | w3 rows 0..63].
// wave (wm,wn): tokens wm*64.., h-cols wn*32..; u/v accs match lanes -> reg silu.
__global__ void __launch_bounds__(256, 4) ffn1_kernel(
    const unsigned short* __restrict__ xb,
    const unsigned short* __restrict__ w1b,
    const unsigned short* __restrict__ w3b,
    const int* __restrict__ tokl, const float* __restrict__ wgtl,
    const int* __restrict__ cnt,
    unsigned short* __restrict__ Hs,
    int h0base, int P, int NT) {
  int e  = blockIdx.x & 7;
  int t  = blockIdx.x >> 3;
  int nt = t % NT, mt = t / NT;
  int ne = cnt[e];
  int m0 = mt * 128;
  if (m0 >= ne) return;
  int offs = 0;
#pragma unroll
  for (int i = 0; i < NE; ++i) offs += (i < e) ? cnt[i] : 0;

  __shared__ __align__(16) unsigned short As[128 * 64];   // XOR-swizzled chunks
  __shared__ __align__(16) unsigned short Bs[128 * 64];
  __shared__ float wgs[128];

  int tid = threadIdx.x, w = tid >> 6, lane = tid & 63;
  int quad = lane >> 4, l16 = lane & 15;
  int wm = w >> 1, wn = w & 1;

  if (tid < 128) {
    int r = m0 + tid;
    wgs[tid] = (r < ne) ? wgtl[e * N_TOK + r] : 0.f;
  }

  int rl = lane >> 3, cc = (lane & 7) ^ rl;   // staging: XOR-swizzled source chunk
  const unsigned short* pa[4];
#pragma unroll
  for (int i = 0; i < 4; ++i) {
    int r = m0 + 32 * w + 8 * i + rl;
    int tok = tokl[e * N_TOK + (r < ne ? r : m0)];
    pa[i] = xb + (size_t)tok * DIM + cc * 8;
  }
  // B rows regular: one base pointer, const strides
  const unsigned short* wsrc = (w < 2) ? w1b : w3b;
  const unsigned short* pb0 =
      wsrc + ((size_t)e * HID + h0base + nt * 64 + ((32 * w) & 63) + rl) * DIM + cc * 8;

  floatx4 u[4][2], v[4][2];
#pragma unroll
  for (int i = 0; i < 4; ++i)
#pragma unroll
    for (int j = 0; j < 2; ++j) { u[i][j] = (floatx4){0,0,0,0}; v[i][j] = (floatx4){0,0,0,0}; }

  for (int k0 = 0; k0 < DIM; k0 += 64) {
#pragma unroll
    for (int i = 0; i < 4; ++i) {
      gl_lds16(pa[i], &As[(32 * w + 8 * i) * 64]);
      gl_lds16(pb0 + (size_t)i * 8 * DIM, &Bs[(32 * w + 8 * i) * 64]);
      pa[i] += 64;
    }
    pb0 += 64;
    __syncthreads();
#pragma unroll
    for (int kk = 0; kk < 2; ++kk) {
      int s = ((4 * kk + quad) ^ (l16 & 7)) * 8;   // all row bases ≡ 0 mod 8
      short8 a[4], b1[2], b3[2];
#pragma unroll
      for (int i = 0; i < 4; ++i)
        a[i] = *(const short8*)&As[(wm * 64 + i * 16 + l16) * 64 + s];
#pragma unroll
      for (int j = 0; j < 2; ++j) {
        b1[j] = *(const short8*)&Bs[(wn * 32 + j * 16 + l16) * 64 + s];
        b3[j] = *(const short8*)&Bs[(64 + wn * 32 + j * 16 + l16) * 64 + s];
      }
#pragma unroll
      for (int i = 0; i < 4; ++i)
#pragma unroll
        for (int j = 0; j < 2; ++j) {
          u[i][j] = MFMA(a[i], b1[j], u[i][j]);
          v[i][j] = MFMA(a[i], b3[j], v[i][j]);
        }
    }
    __syncthreads();
  }

  // ---- epilogue: in-register silu, pack to LDS (reuse As), coalesced store ----
#pragma unroll
  for (int i = 0; i < 4; ++i)
#pragma unroll
    for (int j = 0; j < 2; ++j)
#pragma unroll
      for (int r = 0; r < 4; ++r) {
        int tr = wm * 64 + i * 16 + quad * 4 + r;
        int hc = wn * 32 + j * 16 + l16;
        float uu = u[i][j][r], vv = v[i][j][r];
        float h = (uu / (1.f + __expf(-uu))) * vv * wgs[tr];
        As[tr * 64 + hc] = f2bf(h);
      }
  __syncthreads();
  {
    int row = tid >> 1, half = tid & 1;
    if (m0 + row < ne) {
      const unsigned short* s = &As[row * 64 + half * 32];
      unsigned short* d = Hs + (size_t)(offs + m0 + row) * P + nt * 64 + half * 32;
#pragma unroll
      for (int j = 0; j < 4; ++j) *(uint4*)(d + j * 8) = *(const uint4*)(s + j * 8);
    }
  }
}

// ---------------- GEMM2: out += Hs @ w2^T (gate weight already folded) ----------------
// tile: M=128 tokens x N=128 d-cols, BK=64, K=P.
__global__ void __launch_bounds__(256, 4) ffn2_kernel(
    const unsigned short* __restrict__ Hs,
    const unsigned short* __restrict__ w2b,
    const int* __restrict__ tokl, const int* __restrict__ cnt,
    float* __restrict__ out, int h0base, int P) {
  int e  = blockIdx.x & 7;
  int t  = blockIdx.x >> 3;
  int nt = t & 3, mt = t >> 2;
  int ne = cnt[e];
  int m0 = mt * 128;
  if (m0 >= ne) return;
  int offs = 0;
#pragma unroll
  for (int i = 0; i < NE; ++i) offs += (i < e) ? cnt[i] : 0;

  __shared__ __align__(16) unsigned short As[128 * 64];
  __shared__ __align__(16) unsigned short Bs[128 * 64];
  __shared__ int toks[128];

  int tid = threadIdx.x, w = tid >> 6, lane = tid & 63;
  int quad = lane >> 4, l16 = lane & 15;
  int wm = w >> 1, wn = w & 1;
  if (tid < 128) { int r = m0 + tid; toks[tid] = tokl[e * N_TOK + (r < ne ? r : m0)]; }

  int rl = lane >> 3, cc = (lane & 7) ^ rl;
  int dbase = nt * 128;
  // both A (Hs rows, slot-ordered) and B (w2 rows) are regular: base + const strides
  const unsigned short* pa0 = Hs + (size_t)(offs + m0 + 32 * w + rl) * P + cc * 8;
  const unsigned short* pb0 =
      w2b + ((size_t)e * DIM + dbase + 32 * w + rl) * HID + h0base + cc * 8;

  floatx4 acc[4][4];
#pragma unroll
  for (int i = 0; i < 4; ++i)
#pragma unroll
    for (int j = 0; j < 4; ++j) acc[i][j] = (floatx4){0,0,0,0};

  for (int k0 = 0; k0 < P; k0 += 64) {
#pragma unroll
    for (int i = 0; i < 4; ++i) {
      gl_lds16(pa0 + (size_t)i * 8 * P,   &As[(32 * w + 8 * i) * 64]);
      gl_lds16(pb0 + (size_t)i * 8 * HID, &Bs[(32 * w + 8 * i) * 64]);
    }
    pa0 += 64; pb0 += 64;
    __syncthreads();
#pragma unroll
    for (int kk = 0; kk < 2; ++kk) {
      int s = ((4 * kk + quad) ^ (l16 & 7)) * 8;
      short8 a[4], b[4];
#pragma unroll
      for (int i = 0; i < 4; ++i) {
        a[i] = *(const short8*)&As[(wm * 64 + i * 16 + l16) * 64 + s];
        b[i] = *(const short8*)&Bs[(wn * 64 + i * 16 + l16) * 64 + s];
      }
#pragma unroll
      for (int i = 0; i < 4; ++i)
#pragma unroll
        for (int j = 0; j < 4; ++j)
          acc[i][j] = MFMA(a[i], b[j], acc[i][j]);
    }
    __syncthreads();
  }

#pragma unroll
  for (int i = 0; i < 4; ++i)
#pragma unroll
    for (int j = 0; j < 4; ++j)
#pragma unroll
      for (int r = 0; r < 4; ++r) {
        int row = wm * 64 + i * 16 + quad * 4 + r;
        if (m0 + row < ne)
          atomicAdd(&out[(size_t)toks[row] * DIM + dbase + wn * 64 + j * 16 + l16],
                    acc[i][j][r]);
      }
}

extern "C" void kernel_launch(void* const* d_in, const int* in_sizes, int n_in,
                              void* d_out, int out_size, void* d_ws, size_t ws_size,
                              hipStream_t stream) {
  const float* x  = (const float*)d_in[0];
  const float* gw = (const float*)d_in[1];
  const float* w1 = (const float*)d_in[2];
  const float* w3 = (const float*)d_in[3];
  const float* w2 = (const float*)d_in[4];
  float* out = (float*)d_out;

  const size_t NW = (size_t)NE * HID * DIM;
  char* p = (char*)d_ws;
  unsigned short* w1b = (unsigned short*)p;  p += NW * 2;
  unsigned short* w3b = (unsigned short*)p;  p += NW * 2;
  unsigned short* w2b = (unsigned short*)p;  p += NW * 2;
  unsigned short* xb  = (unsigned short*)p;  p += (size_t)N_TOK * DIM * 2;
  int*      tokl = (int*)p;       p += (size_t)NE * N_TOK * 4;
  float*    wgtl = (float*)p;     p += (size_t)NE * N_TOK * 4;
  unsigned* eidx = (unsigned*)p;  p += (size_t)N_TOK * 4;
  float*    wts  = (float*)p;     p += (size_t)N_TOK * 4;
  int*      cnt  = (int*)p;       p += 256;
  unsigned short* Hs = (unsigned short*)p;
  size_t fixed = (size_t)(p - (char*)d_ws);
  if (ws_size < fixed) return;
  size_t avail = ws_size - fixed;

  const int cands[5] = {1536, 768, 512, 384, 256};
  int P = 0;
  for (int i = 0; i < 5; ++i)
    if ((size_t)(2 * N_TOK + 128) * cands[i] * 2 <= avail) { P = cands[i]; break; }
  if (!P) return;

  hipMemsetAsync(d_out, 0, (size_t)N_TOK * DIM * sizeof(float), stream);
  hipMemsetAsync(cnt, 0, NE * sizeof(int), stream);

  int n4 = (int)(NW / 4);
  cvt_kernel<<<n4 / 256, 256, 0, stream>>>(w1, w1b, n4);
  cvt_kernel<<<n4 / 256, 256, 0, stream>>>(w3, w3b, n4);
  cvt_kernel<<<n4 / 256, 256, 0, stream>>>(w2, w2b, n4);

  gate1_kernel<<<N_TOK / 4, 256, 0, stream>>>(x, gw, xb, eidx, wts);
  gate2_kernel<<<N_TOK / 1024, 256, 0, stream>>>(eidx, wts, tokl, wgtl, cnt);

  for (int h0 = 0; h0 < HID; h0 += P) {
    int NT = P / 64;
    ffn1_kernel<<<8 * MTS * NT, 256, 0, stream>>>(xb, w1b, w3b, tokl, wgtl, cnt, Hs, h0, P, NT);
    ffn2_kernel<<<8 * MTS * 4, 256, 0, stream>>>(Hs, w2b, tokl, cnt, out, h0, P);
  }
}